// Round 11
// baseline (855.031 us; speedup 1.0000x reference)
//
#include <hip/hip_runtime.h>

#define NN 512
#define DD 256

typedef float f32x4 __attribute__((ext_vector_type(4)));
typedef short s16x8 __attribute__((ext_vector_type(8)));

__device__ __forceinline__ unsigned short f2bf(float f) {
    unsigned u = __float_as_uint(f);
    u += 0x7fffu + ((u >> 16) & 1u);   // round-to-nearest-even
    return (unsigned short)(u >> 16);
}
__device__ __forceinline__ unsigned packbf(float a, float b) {
    return ((unsigned)f2bf(b) << 16) | f2bf(a);
}
__device__ __forceinline__ s16x8 pack_bf(const f32x4 v0, const f32x4 v1) {
    s16x8 a;
    a[0] = (short)f2bf(v0[0]); a[1] = (short)f2bf(v0[1]);
    a[2] = (short)f2bf(v0[2]); a[3] = (short)f2bf(v0[3]);
    a[4] = (short)f2bf(v1[0]); a[5] = (short)f2bf(v1[1]);
    a[6] = (short)f2bf(v1[2]); a[7] = (short)f2bf(v1[3]);
    return a;
}

// ---------------------------------------------------------------------------
// K1: hb = h@W1.T + t_bias, hW2 = h@W2.T, hW4 = h@W4.T, w3b = bf16(W3).
// ---------------------------------------------------------------------------
__global__ __launch_bounds__(256) void k1_pre(
    const float* __restrict__ h,  const float* __restrict__ W1,
    const float* __restrict__ W2, const float* __restrict__ W4,
    const float* __restrict__ t_emb, const float* __restrict__ W_t,
    const float* __restrict__ W3,
    float* __restrict__ hb, float* __restrict__ hW2, float* __restrict__ hW4,
    unsigned short* __restrict__ w3b)
{
    __shared__ float xs[8][DD];
    __shared__ float st[DD];
    const int b = blockIdx.x;
    const int t = threadIdx.x;
    if (b < 64) {
        #pragma unroll
        for (int r = 0; r < 8; ++r) xs[r][t] = h[(size_t)(b * 8 + r) * DD + t];
        st[t] = t_emb[t];
        __syncthreads();
        float a1[8], a2[8], a4[8];
        #pragma unroll
        for (int r = 0; r < 8; ++r) { a1[r] = 0.f; a2[r] = 0.f; a4[r] = 0.f; }
        float tb = 0.f;
        for (int d = 0; d < DD; ++d) {
            const float w1 = W1[(size_t)t * DD + d];
            const float w2 = W2[(size_t)t * DD + d];
            const float w4 = W4[(size_t)t * DD + d];
            tb = fmaf(st[d], W_t[(size_t)t * DD + d], tb);
            #pragma unroll
            for (int r = 0; r < 8; ++r) {
                const float x = xs[r][d];
                a1[r] = fmaf(x, w1, a1[r]);
                a2[r] = fmaf(x, w2, a2[r]);
                a4[r] = fmaf(x, w4, a4[r]);
            }
        }
        #pragma unroll
        for (int r = 0; r < 8; ++r) {
            const size_t o = (size_t)(b * 8 + r) * DD + t;
            hb[o] = a1[r] + tb; hW2[o] = a2[r]; hW4[o] = a4[r];
        }
    } else {
        for (int c = t; c < DD * DD / 4; c += 256) {
            const f32x4 v = *reinterpret_cast<const f32x4*>(W3 + (size_t)c * 4);
            *reinterpret_cast<uint2*>(w3b + (size_t)c * 4) =
                make_uint2(packbf(v[0], v[1]), packbf(v[2], v[3]));
        }
    }
}

// ---------------------------------------------------------------------------
// K2 (barrier-free m-split): block = one full i (512 rows), 8 waves, 1/CU.
// B = bf16(W3) in LDS once (R7 swizzle, measured 0 conflicts). After one
// barrier, each wave owns 4x16-row tiles END-TO-END with NO barriers:
//   whole-tile per-lane A prefetch from global (issued before K-loop ->
//   ~2000cy cover), cvt->bf16, 8 kk x 16 n MFMA (acc[16]), wave-local
//   LN/relu/store/gate/exp epilogue (R3-verified geometry), p[16]/z in regs.
// Tail: one block reduction -> non-atomic wacc/zacc store (block owns i).
// __launch_bounds__(512,2): allocator cap 256 regs -> no heuristic spills
// (the R5/R6/R7 killer); block guaranteed 2 waves/SIMD.
// ---------------------------------------------------------------------------
__global__ __launch_bounds__(512, 2) void k2_big(
    const float* __restrict__ e,
    const unsigned short* __restrict__ w3b,
    const float* __restrict__ hb, const float* __restrict__ hW2,
    const float* __restrict__ gate_w, const float* __restrict__ gate_b,
    const float* __restrict__ ln_e_w, const float* __restrict__ ln_e_b,
    float* __restrict__ out_e,
    float* __restrict__ wacc, float* __restrict__ zacc)
{
    __shared__ __align__(16) unsigned char sB[DD * 512];   // 128 KiB bf16, swizzled
    __shared__ float s_hb[DD], s_lnw[DD], s_lnb[DD], s_gw[DD];
    __shared__ float s_pw[8][DD];
    __shared__ float s_zw[8];

    const int i = blockIdx.x;
    const int tid = threadIdx.x;
    const int w = tid >> 6;
    const int l = tid & 63;
    const int l15 = l & 15;
    const int lg = l >> 4;                    // 0..3

    // lane's A base: row = j0 + l15, k-slice base = lg*8
    const float* abase = e + ((size_t)i * NN + (size_t)l15) * DD + lg * 8;

    // ---- prologue: issue tile-0 A loads (16 x dwordx4/lane in flight) ----
    f32x4 av[16];
    {
        const float* ap = abase + (size_t)(w * 16) * DD;
        #pragma unroll
        for (int s = 0; s < 16; ++s)
            av[s] = *reinterpret_cast<const f32x4*>(ap + (s >> 1) * 32 + (s & 1) * 4);
    }

    // ---- stage B -> swizzled LDS (16 chunks/thread) ----
    #pragma unroll
    for (int s = 0; s < 16; ++s) {
        const int c = s * 512 + tid;          // 16B chunk id, 0..8191
        const int col = c >> 5;
        const int kc = c & 31;
        const s16x8 bv = *reinterpret_cast<const s16x8*>(w3b + (size_t)c * 8);
        *reinterpret_cast<s16x8*>(sB + col * 512 + ((kc ^ (col & 15)) << 4)) = bv;
    }
    if (tid < DD) {
        s_hb[tid]  = hb[(size_t)i * DD + tid];
        s_lnw[tid] = ln_e_w[tid];
        s_lnb[tid] = ln_e_b[tid];
        s_gw[tid]  = gate_w[tid];
    }
    __syncthreads();                          // the only pre-tail barrier

    const float gb = gate_b[0];
    float p[16];
    #pragma unroll
    for (int n = 0; n < 16; ++n) p[n] = 0.f;
    float zsum = 0.f;

    for (int t = 0; t < 4; ++t) {
        const int j0 = (t * 8 + w) * 16;      // this wave's 16 rows

        // cvt current tile (av dies into abf)
        s16x8 abf[8];
        #pragma unroll
        for (int kk = 0; kk < 8; ++kk)
            abf[kk] = pack_bf(av[2 * kk], av[2 * kk + 1]);

        // issue NEXT tile's A loads: fly under K-loop + epilogue (~2000cy)
        if (t < 3) {
            const float* apn = abase + (size_t)((t + 1) * 8 + w) * 16 * DD;
            #pragma unroll
            for (int s = 0; s < 16; ++s)
                av[s] = *reinterpret_cast<const f32x4*>(apn + (s >> 1) * 32 + (s & 1) * 4);
        }

        // ---- MFMA: 8 kk x 16 n, B from LDS (0-conflict swizzle) ----
        f32x4 acc[16];
        #pragma unroll
        for (int n = 0; n < 16; ++n) acc[n] = (f32x4){0.f, 0.f, 0.f, 0.f};

        #pragma unroll
        for (int kk = 0; kk < 8; ++kk) {
            const int ksl = kk * 4 + lg;
            #pragma unroll
            for (int n = 0; n < 16; ++n) {
                const int col = n * 16 + l15;
                const s16x8 bfr = *reinterpret_cast<const s16x8*>(
                    sB + col * 512 + ((ksl ^ l15) << 4));
                acc[n] = __builtin_amdgcn_mfma_f32_16x16x32_bf16(abf[kk], bfr, acc[n], 0, 0, 0);
            }
        }

        // ---- wave-local epilogue (rows j0+lg*4+q, cols n*16+l15) ----
        #pragma unroll
        for (int q = 0; q < 4; ++q) {
            const int jrow = j0 + lg * 4 + q;
            const float* h2p = hW2 + (size_t)jrow * DD + l15;
            float s1 = 0.f, s2 = 0.f;
            #pragma unroll
            for (int n = 0; n < 16; ++n) {
                const float v = acc[n][q] + s_hb[n * 16 + l15] + h2p[n * 16];
                acc[n][q] = v;
                s1 += v;
                s2 = fmaf(v, v, s2);
            }
            #pragma unroll
            for (int s = 1; s < 16; s <<= 1) {
                s1 += __shfl_xor(s1, s, 64);
                s2 += __shfl_xor(s2, s, 64);
            }
            const float mu = s1 * (1.f / 256.f);
            const float rs = rsqrtf(s2 * (1.f / 256.f) - mu * mu + 1e-5f);

            float gl = 0.f;
            const size_t rowg = (size_t)(i * NN + jrow) * DD;
            #pragma unroll
            for (int n = 0; n < 16; ++n) {
                const int col = n * 16 + l15;
                float v = (acc[n][q] - mu) * rs * s_lnw[col] + s_lnb[col];
                v = fmaxf(v, 0.f);
                out_e[rowg + col] = v;
                acc[n][q] = v;
                gl = fmaf(v, s_gw[col], gl);
            }
            #pragma unroll
            for (int s = 1; s < 16; s <<= 1) gl += __shfl_xor(gl, s, 64);
            const float ex = __expf(gl + gb);
            zsum += ex;                        // lg-replicated; reduced at end
            #pragma unroll
            for (int n = 0; n < 16; ++n) p[n] = fmaf(ex, acc[n][q], p[n]);
        }
    }

    // ---- per-wave reduce over lg; block combine (non-atomic: block owns i) ----
    #pragma unroll
    for (int n = 0; n < 16; ++n) {
        p[n] += __shfl_xor(p[n], 16, 64);
        p[n] += __shfl_xor(p[n], 32, 64);
    }
    zsum += __shfl_xor(zsum, 16, 64);
    zsum += __shfl_xor(zsum, 32, 64);
    if (lg == 0) {
        #pragma unroll
        for (int n = 0; n < 16; ++n) s_pw[w][n * 16 + l15] = p[n];
    }
    if (l == 0) s_zw[w] = zsum;
    __syncthreads();

    if (tid < DD) {
        float sp = 0.f;
        #pragma unroll
        for (int w8 = 0; w8 < 8; ++w8) sp += s_pw[w8][tid];
        wacc[(size_t)i * DD + tid] = sp;
        if (tid == 0) {
            float zz = 0.f;
            #pragma unroll
            for (int w8 = 0; w8 < 8; ++w8) zz += s_zw[w8];
            zacc[i] = zz;
        }
    }
}

// ---------------------------------------------------------------------------
// K4: h_new = h + relu(LN(hW4 + (wacc/z)@W5.T))
// ---------------------------------------------------------------------------
__global__ __launch_bounds__(256) void k4_final(
    const float* __restrict__ wacc, const float* __restrict__ zacc,
    const float* __restrict__ W5,
    const float* __restrict__ hW4, const float* __restrict__ h,
    const float* __restrict__ ln_h_w, const float* __restrict__ ln_h_b,
    float* __restrict__ out_h)
{
    const int i = blockIdx.x;
    const int k = threadIdx.x;
    __shared__ float xs[DD];
    __shared__ float red[256];

    const float zinv = 1.f / zacc[i];
    xs[k] = wacc[(size_t)i * DD + k] * zinv;
    __syncthreads();
    float a = 0.f;
    for (int d = 0; d < DD; ++d) a = fmaf(xs[d], W5[(size_t)k * DD + d], a);
    const float p = hW4[(size_t)i * DD + k] + a;

    red[k] = p;
    __syncthreads();
    for (int s = 128; s > 0; s >>= 1) {
        if (k < s) red[k] += red[k + s];
        __syncthreads();
    }
    const float mu = red[0] * (1.f / 256.f);
    __syncthreads();
    const float d0 = p - mu;
    red[k] = d0 * d0;
    __syncthreads();
    for (int s = 128; s > 0; s >>= 1) {
        if (k < s) red[k] += red[k + s];
        __syncthreads();
    }
    const float rs = rsqrtf(red[0] * (1.f / 256.f) + 1e-5f);
    float v = d0 * rs * ln_h_w[k] + ln_h_b[k];
    v = fmaxf(v, 0.f);
    out_h[(size_t)i * DD + k] = h[(size_t)i * DD + k] + v;
}

// ---------------------------------------------------------------------------
extern "C" void kernel_launch(void* const* d_in, const int* in_sizes, int n_in,
                              void* d_out, int out_size, void* d_ws, size_t ws_size,
                              hipStream_t stream)
{
    const float* h      = (const float*)d_in[0];
    const float* e      = (const float*)d_in[1];
    const float* t_emb  = (const float*)d_in[2];
    const float* W1     = (const float*)d_in[3];
    const float* W2     = (const float*)d_in[4];
    const float* W3     = (const float*)d_in[5];
    const float* W_t    = (const float*)d_in[6];
    const float* W4     = (const float*)d_in[7];
    const float* W5     = (const float*)d_in[8];
    const float* gate_w = (const float*)d_in[9];
    const float* gate_b = (const float*)d_in[10];
    const float* ln_e_w = (const float*)d_in[11];
    const float* ln_e_b = (const float*)d_in[12];
    const float* ln_h_w = (const float*)d_in[13];
    const float* ln_h_b = (const float*)d_in[14];

    float* out_h = (float*)d_out;
    float* out_e = out_h + NN * DD;

    // workspace layout (~2.3 MiB)
    float* wsf  = (float*)d_ws;
    float* hb   = wsf;                        // 131072 (hW1 + t_bias)
    float* hW2  = hb + NN * DD;               // 131072
    float* hW4  = hW2 + NN * DD;              // 131072
    float* wacc = hW4 + NN * DD;              // 131072
    float* zacc = wacc + NN * DD;             // 512
    unsigned short* w3b = (unsigned short*)(zacc + NN);  // 65536 ushort

    k1_pre<<<65, 256, 0, stream>>>(h, W1, W2, W4, t_emb, W_t, W3,
                                   hb, hW2, hW4, w3b);
    k2_big<<<512, 512, 0, stream>>>(e, w3b, hb, hW2, gate_w, gate_b,
                                    ln_e_w, ln_e_b, out_e, wacc, zacc);
    k4_final<<<512, 256, 0, stream>>>(wacc, zacc, W5, hW4, h,
                                      ln_h_w, ln_h_b, out_h);
}

// Round 12
// 282.539 us; speedup vs baseline: 3.0262x; 3.0262x over previous
//
#include <hip/hip_runtime.h>

#define NN 512
#define DD 256

typedef float f32x4 __attribute__((ext_vector_type(4)));
typedef short s16x8 __attribute__((ext_vector_type(8)));

__device__ __forceinline__ unsigned short f2bf(float f) {
    unsigned u = __float_as_uint(f);
    u += 0x7fffu + ((u >> 16) & 1u);   // round-to-nearest-even
    return (unsigned short)(u >> 16);
}
__device__ __forceinline__ float bf2f(unsigned short s) {
    return __uint_as_float(((unsigned)s) << 16);
}
__device__ __forceinline__ unsigned packbf(float a, float b) {
    return ((unsigned)f2bf(b) << 16) | f2bf(a);
}
__device__ __forceinline__ s16x8 pack_bf(const f32x4 v0, const f32x4 v1) {
    s16x8 a;
    a[0] = (short)f2bf(v0[0]); a[1] = (short)f2bf(v0[1]);
    a[2] = (short)f2bf(v0[2]); a[3] = (short)f2bf(v0[3]);
    a[4] = (short)f2bf(v1[0]); a[5] = (short)f2bf(v1[1]);
    a[6] = (short)f2bf(v1[2]); a[7] = (short)f2bf(v1[3]);
    return a;
}
// async global->LDS, 16B per lane; lds base wave-uniform, g per-lane
__device__ __forceinline__ void gl_lds16(const float* g, float* lds) {
    __builtin_amdgcn_global_load_lds(
        (const __attribute__((address_space(1))) void*)g,
        (__attribute__((address_space(3))) void*)lds, 16, 0, 0);
}

// ---------------------------------------------------------------------------
// K1: hb = h@W1.T + t_bias, hW2 = h@W2.T, hW4 = h@W4.T, w3b = bf16(W3),
//     zero the softmax accumulators (wacc, zacc).
// ---------------------------------------------------------------------------
__global__ __launch_bounds__(256) void k1_pre(
    const float* __restrict__ h,  const float* __restrict__ W1,
    const float* __restrict__ W2, const float* __restrict__ W4,
    const float* __restrict__ t_emb, const float* __restrict__ W_t,
    const float* __restrict__ W3,
    float* __restrict__ hb, float* __restrict__ hW2, float* __restrict__ hW4,
    unsigned short* __restrict__ w3b,
    float* __restrict__ wacc, float* __restrict__ zacc)
{
    __shared__ float xs[8][DD];
    __shared__ float st[DD];
    const int b = blockIdx.x;
    const int t = threadIdx.x;
    if (b < 64) {
        #pragma unroll
        for (int r = 0; r < 8; ++r) xs[r][t] = h[(size_t)(b * 8 + r) * DD + t];
        st[t] = t_emb[t];
        __syncthreads();
        float a1[8], a2[8], a4[8];
        #pragma unroll
        for (int r = 0; r < 8; ++r) { a1[r] = 0.f; a2[r] = 0.f; a4[r] = 0.f; }
        float tb = 0.f;
        for (int d = 0; d < DD; ++d) {
            const float w1 = W1[(size_t)t * DD + d];
            const float w2 = W2[(size_t)t * DD + d];
            const float w4 = W4[(size_t)t * DD + d];
            tb = fmaf(st[d], W_t[(size_t)t * DD + d], tb);
            #pragma unroll
            for (int r = 0; r < 8; ++r) {
                const float x = xs[r][d];
                a1[r] = fmaf(x, w1, a1[r]);
                a2[r] = fmaf(x, w2, a2[r]);
                a4[r] = fmaf(x, w4, a4[r]);
            }
        }
        #pragma unroll
        for (int r = 0; r < 8; ++r) {
            const size_t o = (size_t)(b * 8 + r) * DD + t;
            hb[o] = a1[r] + tb; hW2[o] = a2[r]; hW4[o] = a4[r];
        }
    } else if (b == 64) {
        for (int c = t; c < DD * DD / 4; c += 256) {
            const f32x4 v = *reinterpret_cast<const f32x4*>(W3 + (size_t)c * 4);
            *reinterpret_cast<uint2*>(w3b + (size_t)c * 4) =
                make_uint2(packbf(v[0], v[1]), packbf(v[2], v[3]));
        }
    } else {
        const f32x4 zero = (f32x4){0.f, 0.f, 0.f, 0.f};
        for (int c = t; c < NN * DD / 4; c += 256)
            *reinterpret_cast<f32x4*>(wacc + (size_t)c * 4) = zero;
        if (t < 256) { zacc[t] = 0.f; zacc[t + 256] = 0.f; }
    }
}

// ---------------------------------------------------------------------------
// K2: pre = e@W3.T + hb[i] + hW2[j]; e_new = relu(LN(pre)); fused no-max
// softmax partials -> atomicAdd into wacc[i,:], zacc[i].
// Block = 32 rows, 4 n-split waves, acc[2][4] (32 AGPR), depth-4 B prefetch.
// NEW vs R8/R9: A staged via global_load_lds width=16 (async DMA, f32, no
// VGPR round-trip / no stage-cvt VALU). LDS stays LINEAR; the GLOBAL source
// is lane-permuted (chunk = lane ^ (row&7), m173 pattern) so K-loop b128
// reads spread 16 rows over 8 bank-groups (2-way = free). cvt->bf16 happens
// at fragment assembly (hidden under MFMA). sH2 dropped (R9: direct-L2 hW2
// identical) -> LDS ~37KB -> 4 blocks/CU for phase-decorrelated DMA.
// ---------------------------------------------------------------------------
__global__ __launch_bounds__(256) void k2_big(
    const float* __restrict__ e,
    const unsigned short* __restrict__ w3b,
    const float* __restrict__ hb, const float* __restrict__ hW2,
    const float* __restrict__ gate_w, const float* __restrict__ gate_b,
    const float* __restrict__ ln_e_w, const float* __restrict__ ln_e_b,
    float* __restrict__ out_e,
    float* __restrict__ wacc, float* __restrict__ zacc)
{
    const int b = blockIdx.x;
    const int row_base = b * 32;              // flat row = i*512 + j
    const int i = row_base >> 9;
    const int tid = threadIdx.x;
    const int w = tid >> 6;
    const int l = tid & 63;
    const int l15 = l & 15;
    const int lg = l >> 4;                    // 0..3

    __shared__ __align__(16) float sAf[32 * 256];   // 32 KiB f32 A-tile, src-permuted
    __shared__ unsigned short s_hbu[DD];
    __shared__ float s_lnw[DD], s_lnb[DD], s_gw[DD];
    __shared__ float s_part[32][4][2];
    __shared__ float s_glog[32][4];

    // ---- stage A via async DMA: wave w stages rows w*8..w*8+7.
    //      lane l fetches global chunk (l ^ (r&7)) -> lds slot l (linear). ----
    {
        const float* esrc = e + (size_t)row_base * DD;
        #pragma unroll
        for (int t = 0; t < 8; ++t) {
            const int r = w * 8 + t;
            gl_lds16(esrc + (size_t)r * DD + ((l ^ (r & 7)) << 2), sAf + r * 256);
        }
    }

    // ---- B: 4 K-slot fragments (depth-4 prefetch base) ----
    const unsigned short* bp = w3b + (size_t)(w * 64 + l15) * DD + lg * 8;
    s16x8 bb[4][4];
    #pragma unroll
    for (int kk = 0; kk < 4; ++kk)
        #pragma unroll
        for (int n = 0; n < 4; ++n)
            bb[kk][n] = *reinterpret_cast<const s16x8*>(bp + (size_t)n * 16 * DD + kk * 32);

    const float gb = gate_b[0];
    s_lnw[tid] = ln_e_w[tid];
    s_lnb[tid] = ln_e_b[tid];
    s_gw[tid]  = gate_w[tid];
    s_hbu[tid] = f2bf(hb[(size_t)i * DD + tid]);
    __syncthreads();   // drains DMA (vmcnt) + ds writes

    // ---- MFMA K-loop: A from LDS (f32, permuted slots) + cvt at assembly ----
    f32x4 acc[2][4];
    #pragma unroll
    for (int m = 0; m < 2; ++m)
        #pragma unroll
        for (int n = 0; n < 4; ++n)
            acc[m][n] = (f32x4){0.f, 0.f, 0.f, 0.f};

    #pragma unroll
    for (int kk = 0; kk < 8; ++kk) {
        s16x8 afr[2];
        #pragma unroll
        for (int m = 0; m < 2; ++m) {
            const int r = m * 16 + l15;
            const int c0 = kk * 8 + lg * 2;           // logical 16B chunk
            const int s0 = c0 ^ (r & 7);
            const int s1 = (c0 + 1) ^ (r & 7);
            const f32x4 v0 = *reinterpret_cast<const f32x4*>(sAf + r * 256 + s0 * 4);
            const f32x4 v1 = *reinterpret_cast<const f32x4*>(sAf + r * 256 + s1 * 4);
            afr[m] = pack_bf(v0, v1);
        }
        #pragma unroll
        for (int n = 0; n < 4; ++n)
            #pragma unroll
            for (int m = 0; m < 2; ++m)
                acc[m][n] = __builtin_amdgcn_mfma_f32_16x16x32_bf16(afr[m], bb[kk & 3][n], acc[m][n], 0, 0, 0);
        if (kk < 4) {
            #pragma unroll
            for (int n = 0; n < 4; ++n)
                bb[kk & 3][n] = *reinterpret_cast<const s16x8*>(bp + (size_t)n * 16 * DD + (kk + 4) * 32);
        }
    }

    // ---- epilogue A: biases (hW2 f32 direct from L2) + LN partial sums ----
    float hbn[4];
    #pragma unroll
    for (int n = 0; n < 4; ++n) hbn[n] = bf2f(s_hbu[w * 64 + n * 16 + l15]);

    #pragma unroll
    for (int m = 0; m < 2; ++m) {
        #pragma unroll
        for (int q = 0; q < 4; ++q) {
            const int r = m * 16 + lg * 4 + q;
            const int j = (row_base + r) & 511;
            const float* h2p = hW2 + (size_t)j * DD + w * 64 + l15;
            float s1 = 0.f, s2 = 0.f;
            #pragma unroll
            for (int n = 0; n < 4; ++n) {
                const float v = acc[m][n][q] + hbn[n] + h2p[n * 16];
                acc[m][n][q] = v;
                s1 += v;
                s2 = fmaf(v, v, s2);
            }
            #pragma unroll
            for (int s = 1; s < 16; s <<= 1) {
                s1 += __shfl_xor(s1, s, 64);
                s2 += __shfl_xor(s2, s, 64);
            }
            if (l15 == 0) { s_part[r][w][0] = s1; s_part[r][w][1] = s2; }
        }
    }
    __syncthreads();

    // ---- epilogue B: stats (redundant broadcast), normalize, relu, store, gate ----
    #pragma unroll
    for (int m = 0; m < 2; ++m) {
        #pragma unroll
        for (int q = 0; q < 4; ++q) {
            const int r = m * 16 + lg * 4 + q;
            float S1 = 0.f, S2 = 0.f;
            #pragma unroll
            for (int ww = 0; ww < 4; ++ww) { S1 += s_part[r][ww][0]; S2 += s_part[r][ww][1]; }
            const float mu = S1 * (1.f / 256.f);
            const float rs = rsqrtf(S2 * (1.f / 256.f) - mu * mu + 1e-5f);
            const size_t rowg = (size_t)(row_base + r);
            float gl = 0.f;
            #pragma unroll
            for (int n = 0; n < 4; ++n) {
                const int c = w * 64 + n * 16 + l15;
                float v = (acc[m][n][q] - mu) * rs * s_lnw[c] + s_lnb[c];
                v = fmaxf(v, 0.f);
                acc[m][n][q] = v;
                out_e[rowg * DD + c] = v;
                gl = fmaf(v, s_gw[c], gl);
            }
            #pragma unroll
            for (int s = 1; s < 16; s <<= 1) gl += __shfl_xor(gl, s, 64);
            if (l15 == 0) s_glog[r][w] = gl;
        }
    }
    __syncthreads();

    // ---- fused no-max softmax partials ----
    float p[4] = {0.f, 0.f, 0.f, 0.f};
    float zl = 0.f;
    #pragma unroll
    for (int m = 0; m < 2; ++m) {
        #pragma unroll
        for (int q = 0; q < 4; ++q) {
            const int r = m * 16 + lg * 4 + q;
            const float lv = gb + s_glog[r][0] + s_glog[r][1] + s_glog[r][2] + s_glog[r][3];
            const float ex = __expf(lv);
            zl += ex;
            #pragma unroll
            for (int n = 0; n < 4; ++n) p[n] = fmaf(ex, acc[m][n][q], p[n]);
        }
    }
    #pragma unroll
    for (int n = 0; n < 4; ++n) {
        p[n] += __shfl_xor(p[n], 16, 64);
        p[n] += __shfl_xor(p[n], 32, 64);
    }
    zl += __shfl_xor(zl, 16, 64);
    zl += __shfl_xor(zl, 32, 64);
    if (lg == 0) {
        #pragma unroll
        for (int n = 0; n < 4; ++n)
            atomicAdd(&wacc[(size_t)i * DD + w * 64 + n * 16 + l15], p[n]);
    }
    if (w == 0 && l == 0) atomicAdd(&zacc[i], zl);
}

// ---------------------------------------------------------------------------
// K4: h_new = h + relu(LN(hW4 + (wacc/z)@W5.T))
// ---------------------------------------------------------------------------
__global__ __launch_bounds__(256) void k4_final(
    const float* __restrict__ wacc, const float* __restrict__ zacc,
    const float* __restrict__ W5,
    const float* __restrict__ hW4, const float* __restrict__ h,
    const float* __restrict__ ln_h_w, const float* __restrict__ ln_h_b,
    float* __restrict__ out_h)
{
    const int i = blockIdx.x;
    const int k = threadIdx.x;
    __shared__ float xs[DD];
    __shared__ float red[256];

    const float zinv = 1.f / zacc[i];
    xs[k] = wacc[(size_t)i * DD + k] * zinv;
    __syncthreads();
    float a = 0.f;
    for (int d = 0; d < DD; ++d) a = fmaf(xs[d], W5[(size_t)k * DD + d], a);
    const float p = hW4[(size_t)i * DD + k] + a;

    red[k] = p;
    __syncthreads();
    for (int s = 128; s > 0; s >>= 1) {
        if (k < s) red[k] += red[k + s];
        __syncthreads();
    }
    const float mu = red[0] * (1.f / 256.f);
    __syncthreads();
    const float d0 = p - mu;
    red[k] = d0 * d0;
    __syncthreads();
    for (int s = 128; s > 0; s >>= 1) {
        if (k < s) red[k] += red[k + s];
        __syncthreads();
    }
    const float rs = rsqrtf(red[0] * (1.f / 256.f) + 1e-5f);
    float v = d0 * rs * ln_h_w[k] + ln_h_b[k];
    v = fmaxf(v, 0.f);
    out_h[(size_t)i * DD + k] = h[(size_t)i * DD + k] + v;
}

// ---------------------------------------------------------------------------
extern "C" void kernel_launch(void* const* d_in, const int* in_sizes, int n_in,
                              void* d_out, int out_size, void* d_ws, size_t ws_size,
                              hipStream_t stream)
{
    const float* h      = (const float*)d_in[0];
    const float* e      = (const float*)d_in[1];
    const float* t_emb  = (const float*)d_in[2];
    const float* W1     = (const float*)d_in[3];
    const float* W2     = (const float*)d_in[4];
    const float* W3     = (const float*)d_in[5];
    const float* W_t    = (const float*)d_in[6];
    const float* W4     = (const float*)d_in[7];
    const float* W5     = (const float*)d_in[8];
    const float* gate_w = (const float*)d_in[9];
    const float* gate_b = (const float*)d_in[10];
    const float* ln_e_w = (const float*)d_in[11];
    const float* ln_e_b = (const float*)d_in[12];
    const float* ln_h_w = (const float*)d_in[13];
    const float* ln_h_b = (const float*)d_in[14];

    float* out_h = (float*)d_out;
    float* out_e = out_h + NN * DD;

    // workspace layout (~2.3 MiB)
    float* wsf  = (float*)d_ws;
    float* hb   = wsf;                        // 131072 (hW1 + t_bias)
    float* hW2  = hb + NN * DD;               // 131072
    float* hW4  = hW2 + NN * DD;              // 131072
    float* wacc = hW4 + NN * DD;              // 131072
    float* zacc = wacc + NN * DD;             // 512
    unsigned short* w3b = (unsigned short*)(zacc + NN);  // 65536 ushort

    k1_pre<<<66, 256, 0, stream>>>(h, W1, W2, W4, t_emb, W_t, W3,
                                   hb, hW2, hW4, w3b, wacc, zacc);
    k2_big<<<8192, 256, 0, stream>>>(e, w3b, hb, hW2, gate_w, gate_b,
                                     ln_e_w, ln_e_b, out_e, wacc, zacc);
    k4_final<<<512, 256, 0, stream>>>(wacc, zacc, W5, hW4, h,
                                      ln_h_w, ln_h_b, out_h);
}